// Round 5
// baseline (97.315 us; speedup 1.0000x reference)
//
#include <hip/hip_runtime.h>

constexpr int H = 192, W = 192, D = 192;
constexpr int BH = 8, BW = 8, BZ = 16;     // output tile per block
constexpr int TY = 16, TX = 16, TZ = 24;   // staged: x/y halo -4..+11, z -4..+19
constexpr int TILE_N = TY * TX * TZ;       // 6144 dwords = 24 KB
constexpr int BASE_MAX_FAST = TILE_N - 2 - TZ * (TX + 1);  // 5734: max legal fast-path base

// Exact reference semantics for one voxel, all-global (fallback path).
__device__ __forceinline__ float ref_voxel(const float* __restrict__ I,
                                           float x, float y, float zf)
{
    int fx = (int)floorf(x), fy = (int)floorf(y), fz = (int)floorf(zf);
    int x0 = min(max(fx, 0), W + 1), x1 = min(max(fx + 1, 0), W + 1);
    int y0 = min(max(fy, 0), H + 1), y1 = min(max(fy + 1, 0), H + 1);
    int zp0 = min(max(fz, 0), D + 1), zp1 = min(max(fz + 1, 0), D + 1);
    float dx = (float)x1 - x, dy = (float)y1 - y, dz = (float)zp1 - zf;
    int xi0 = x0 - 1, xi1 = x1 - 1, yi0 = y0 - 1, yi1 = y1 - 1;
    int zi = zp0 - 1, zj = zp1 - 1;
    float ax0 = ((unsigned)xi0 < (unsigned)W) ? dx       : 0.f;
    float ax1 = ((unsigned)xi1 < (unsigned)W) ? 1.f - dx : 0.f;
    float ay0 = ((unsigned)yi0 < (unsigned)H) ? dy       : 0.f;
    float ay1 = ((unsigned)yi1 < (unsigned)H) ? 1.f - dy : 0.f;
    float az0 = ((unsigned)zi  < (unsigned)D) ? dz       : 0.f;
    float az1 = ((unsigned)zj  < (unsigned)D) ? 1.f - dz : 0.f;
    int xc0 = min(max(xi0, 0), W - 1), xc1 = min(max(xi1, 0), W - 1);
    int yc0 = min(max(yi0, 0), H - 1), yc1 = min(max(yi1, 0), H - 1);
    int zc0 = min(max(zi, 0), D - 1),  zc1 = min(max(zj, 0), D - 1);
    const float* r00 = I + (yc0 * W + xc0) * D;
    const float* r01 = I + (yc0 * W + xc1) * D;
    const float* r10 = I + (yc1 * W + xc0) * D;
    const float* r11 = I + (yc1 * W + xc1) * D;
    float s00 = az0 * r00[zc0] + az1 * r00[zc1];
    float s01 = az0 * r01[zc0] + az1 * r01[zc1];
    float s10 = az0 * r10[zc0] + az1 * r10[zc1];
    float s11 = az0 * r11[zc0] + az1 * r11[zc1];
    return ay0 * (ax0 * s00 + ax1 * s01) + ay1 * (ax0 * s10 + ax1 * s11);
}

__global__ __launch_bounds__(256, 4) void st_tile(
    const float* __restrict__ I,
    const float* __restrict__ dxt,
    const float* __restrict__ dyt,
    const float* __restrict__ dzt,
    float* __restrict__ out)
{
    __shared__ float tile[TILE_N];   // 24 KB

    const int tid = threadIdx.x;
    const int bx = blockIdx.x, by = blockIdx.y, bz = blockIdx.z;
    const int w0 = bx * BW, h0 = by * BH, z0 = bz * BZ;
    const int xg0 = w0 - 4, yg0 = h0 - 4, zg0 = z0 - 4;

    const int zq = tid & 3, wl = (tid >> 2) & 7, hl = tid >> 5;
    const int h = h0 + hl, w = w0 + wl, z = z0 + zq * 4;
    const int t4 = (h * W + w) * (D / 4) + (z >> 2);

    const bool interior = (bx >= 1) & (bx <= 22) & (by >= 1) & (by <= 22)
                        & (bz >= 1) & (bz <= 10);

    float4 vx, vy, vz;
    float ro[4];

    if (interior) {
        // ---- staging: issue ALL loads, fence, then write LDS ----
        float4 vals[6];
        {
            const float* p0 = I + ((yg0 * W + xg0) * D + zg0);
            #pragma unroll
            for (int it = 0; it < 6; ++it) {
                int g = it * 256 + tid;
                int row = g / 6, c = g - row * 6;
                int ry = row >> 4, rx = row & 15;
                vals[it] = *reinterpret_cast<const float4*>(p0 + (ry * W + rx) * D + c * 4);
            }
        }
        vx = reinterpret_cast<const float4*>(dxt)[t4];
        vy = reinterpret_cast<const float4*>(dyt)[t4];
        vz = reinterpret_cast<const float4*>(dzt)[t4];
        __builtin_amdgcn_sched_barrier(0);
        #pragma unroll
        for (int it = 0; it < 6; ++it) {
            *reinterpret_cast<float4*>(
                reinterpret_cast<char*>(tile) + (size_t)(it * 4096 + tid * 16)) = vals[it];
        }
        __syncthreads();

        float rxj[4] = {vx.x, vx.y, vx.z, vx.w};
        float ryj[4] = {vy.x, vy.y, vy.z, vy.w};
        float rzj[4] = {vz.x, vz.y, vz.z, vz.w};

        // ---- phase 1: all addresses + fracs ----
        int   base[4];
        float tx[4], ty[4], tz[4];
        bool  okj[4];
        #pragma unroll
        for (int j = 0; j < 4; ++j) {
            float ux = rxj[j] + (float)(wl + 4);
            float uy = ryj[j] + (float)(hl + 4);
            float uz = rzj[j] + (float)(zq * 4 + j + 4);
            float fxf = floorf(ux), fyf = floorf(uy), fzf = floorf(uz);
            int lx = (int)fxf, ly = (int)fyf, lz = (int)fzf;
            tx[j] = ux - fxf; ty[j] = uy - fyf; tz[j] = uz - fzf;
            okj[j] = ((unsigned)lx <= (unsigned)(TX - 2))
                   & ((unsigned)ly <= (unsigned)(TY - 2))
                   & ((unsigned)lz <= (unsigned)(TZ - 2));
            int b = (ly * TX + lx) * TZ + lz;
            base[j] = min(max(b, 0), BASE_MAX_FAST);   // loads always legal
        }

        // ---- phase 2: ALL 32 LDS loads into registers ----
        float A0[4], A1[4], B0[4], B1[4], C0[4], C1[4], E0[4], E1[4];
        #pragma unroll
        for (int j = 0; j < 4; ++j) {
            int b = base[j];
            A0[j] = tile[b];                 A1[j] = tile[b + 1];
            B0[j] = tile[b + TZ];            B1[j] = tile[b + TZ + 1];
            C0[j] = tile[b + TX * TZ];       C1[j] = tile[b + TX * TZ + 1];
            E0[j] = tile[b + TX * TZ + TZ];  E1[j] = tile[b + TX * TZ + TZ + 1];
        }
        __builtin_amdgcn_sched_barrier(0);   // forbid re-sinking loads into uses

        // ---- phase 3: FMA trees ----
        #pragma unroll
        for (int j = 0; j < 4; ++j) {
            float wz1 = tz[j], wz0 = 1.f - wz1;
            float wx1 = tx[j], wx0 = 1.f - wx1;
            float wy1 = ty[j], wy0 = 1.f - wy1;
            float s00 = wz0 * A0[j] + wz1 * A1[j];
            float s01 = wz0 * B0[j] + wz1 * B1[j];
            float s10 = wz0 * C0[j] + wz1 * C1[j];
            float s11 = wz0 * E0[j] + wz1 * E1[j];
            ro[j] = wy0 * (wx0 * s00 + wx1 * s01) + wy1 * (wx0 * s10 + wx1 * s11);
        }

        // ---- rare out-of-halo fallback (exact reference) ----
        #pragma unroll
        for (int j = 0; j < 4; ++j) {
            if (__builtin_expect(!okj[j], 0)) {
                ro[j] = ref_voxel(I, rxj[j] + (float)(w + 1),
                                     ryj[j] + (float)(h + 1),
                                     rzj[j] + (float)(z + j + 1));
            }
        }
    } else {
        // ---- border staging: per-element clamped ----
        float4 vals[6];
        #pragma unroll
        for (int it = 0; it < 6; ++it) {
            int g = it * 256 + tid;
            int row = g / 6, c = g - row * 6;
            int ry = row >> 4, rx = row & 15;
            int gy = min(max(yg0 + ry, 0), H - 1);
            int gx = min(max(xg0 + rx, 0), W - 1);
            const float* rp = I + (gy * W + gx) * D;
            int zb = zg0 + c * 4;
            vals[it] = make_float4(rp[min(max(zb + 0, 0), D - 1)],
                                   rp[min(max(zb + 1, 0), D - 1)],
                                   rp[min(max(zb + 2, 0), D - 1)],
                                   rp[min(max(zb + 3, 0), D - 1)]);
        }
        vx = reinterpret_cast<const float4*>(dxt)[t4];
        vy = reinterpret_cast<const float4*>(dyt)[t4];
        vz = reinterpret_cast<const float4*>(dzt)[t4];
        __builtin_amdgcn_sched_barrier(0);
        #pragma unroll
        for (int it = 0; it < 6; ++it) {
            *reinterpret_cast<float4*>(
                reinterpret_cast<char*>(tile) + (size_t)(it * 4096 + tid * 16)) = vals[it];
        }
        __syncthreads();

        float rxj[4] = {vx.x, vx.y, vx.z, vx.w};
        float ryj[4] = {vy.x, vy.y, vy.z, vy.w};
        float rzj[4] = {vz.x, vz.y, vz.z, vz.w};

        // ---- border compute: full clamp + folded weights, per-j batched loads ----
        #pragma unroll
        for (int j = 0; j < 4; ++j) {
            float x = rxj[j] + (float)(w + 1);
            float y = ryj[j] + (float)(h + 1);
            float zf = rzj[j] + (float)(z + j + 1);

            int fx = (int)floorf(x), fy = (int)floorf(y), fz = (int)floorf(zf);
            int x0 = min(max(fx, 0), W + 1), x1 = min(max(fx + 1, 0), W + 1);
            int y0 = min(max(fy, 0), H + 1), y1 = min(max(fy + 1, 0), H + 1);
            int zp0 = min(max(fz, 0), D + 1), zp1 = min(max(fz + 1, 0), D + 1);

            float dx = (float)x1 - x, dy = (float)y1 - y, dz = (float)zp1 - zf;

            int xi0 = x0 - 1, xi1 = x1 - 1, yi0 = y0 - 1, yi1 = y1 - 1;
            int zi = zp0 - 1, zj2 = zp1 - 1;

            float ax0 = ((unsigned)xi0 < (unsigned)W) ? dx       : 0.f;
            float ax1 = ((unsigned)xi1 < (unsigned)W) ? 1.f - dx : 0.f;
            float ay0 = ((unsigned)yi0 < (unsigned)H) ? dy       : 0.f;
            float ay1 = ((unsigned)yi1 < (unsigned)H) ? 1.f - dy : 0.f;
            float az0 = ((unsigned)zi  < (unsigned)D) ? dz       : 0.f;
            float az1 = ((unsigned)zj2 < (unsigned)D) ? 1.f - dz : 0.f;

            int xc0 = min(max(xi0, 0), W - 1), xc1 = min(max(xi1, 0), W - 1);
            int yc0 = min(max(yi0, 0), H - 1), yc1 = min(max(yi1, 0), H - 1);
            int zc  = min(max(zi, 0), D - 2);

            bool zlo = (zi <= D - 2);
            bool zhi = (zi >= 0);

            int lx0 = xc0 - xg0, lx1 = xc1 - xg0;
            int ly0 = yc0 - yg0, ly1 = yc1 - yg0;
            int lz  = zc - zg0;

            bool ok = ((unsigned)lx0 <= (unsigned)(TX - 1))
                    & ((unsigned)lx1 <= (unsigned)(TX - 1))
                    & ((unsigned)ly0 <= (unsigned)(TY - 1))
                    & ((unsigned)ly1 <= (unsigned)(TY - 1))
                    & ((unsigned)lz  <= (unsigned)(TZ - 2));

            // clamp bases so loads are always legal; bad lanes overwritten below
            int b00 = min(max((ly0 * TX + lx0) * TZ + lz, 0), TILE_N - 2);
            int b01 = min(max((ly0 * TX + lx1) * TZ + lz, 0), TILE_N - 2);
            int b10 = min(max((ly1 * TX + lx0) * TZ + lz, 0), TILE_N - 2);
            int b11 = min(max((ly1 * TX + lx1) * TZ + lz, 0), TILE_N - 2);

            float a0 = tile[b00], a1 = tile[b00 + 1];
            float b0 = tile[b01], b1 = tile[b01 + 1];
            float c0 = tile[b10], c1 = tile[b10 + 1];
            float d0 = tile[b11], d1 = tile[b11 + 1];
            __builtin_amdgcn_sched_barrier(0);

            float v000 = zlo ? a0 : a1, v001 = zhi ? a1 : a0;
            float v010 = zlo ? b0 : b1, v011 = zhi ? b1 : b0;
            float v100 = zlo ? c0 : c1, v101 = zhi ? c1 : c0;
            float v110 = zlo ? d0 : d1, v111 = zhi ? d1 : d0;
            float s00 = az0 * v000 + az1 * v001;
            float s01 = az0 * v010 + az1 * v011;
            float s10 = az0 * v100 + az1 * v101;
            float s11 = az0 * v110 + az1 * v111;
            float r = ay0 * (ax0 * s00 + ax1 * s01)
                    + ay1 * (ax0 * s10 + ax1 * s11);

            ro[j] = __builtin_expect(ok, 1) ? r : ref_voxel(I, x, y, zf);
        }
    }

    reinterpret_cast<float4*>(out)[t4] = make_float4(ro[0], ro[1], ro[2], ro[3]);
}

extern "C" void kernel_launch(void* const* d_in, const int* in_sizes, int n_in,
                              void* d_out, int out_size, void* d_ws, size_t ws_size,
                              hipStream_t stream) {
    const float* I   = (const float*)d_in[0];
    const float* dxt = (const float*)d_in[1];
    const float* dyt = (const float*)d_in[2];
    const float* dzt = (const float*)d_in[3];
    float* out = (float*)d_out;

    dim3 grid(W / BW, H / BH, D / BZ);   // 24 x 24 x 12
    hipLaunchKernelGGL(st_tile, grid, dim3(256), 0, stream,
                       I, dxt, dyt, dzt, out);
}

// Round 6
// 48.937 us; speedup vs baseline: 1.9886x; 1.9886x over previous
//
#include <hip/hip_runtime.h>

constexpr int H = 192, W = 192, D = 192;
constexpr int BH = 16, BW = 16, BZ = 16;     // output tile per block
constexpr int TY = 24, TX = 24, TZ = 24;     // staged tile: halo -4..+19 each axis
constexpr int TILE_N = TY * TX * TZ;         // 13824 dwords = 54 KB
constexpr int NINSTR = TILE_N / 4 / 64;      // 54 wave-instructions of 64 chunks

// Exact reference semantics for one voxel, all-global (fallback path).
__device__ __forceinline__ float ref_voxel(const float* __restrict__ I,
                                           float x, float y, float zf)
{
    int fx = (int)floorf(x), fy = (int)floorf(y), fz = (int)floorf(zf);
    int x0 = min(max(fx, 0), W + 1), x1 = min(max(fx + 1, 0), W + 1);
    int y0 = min(max(fy, 0), H + 1), y1 = min(max(fy + 1, 0), H + 1);
    int zp0 = min(max(fz, 0), D + 1), zp1 = min(max(fz + 1, 0), D + 1);
    float dx = (float)x1 - x, dy = (float)y1 - y, dz = (float)zp1 - zf;
    int xi0 = x0 - 1, xi1 = x1 - 1, yi0 = y0 - 1, yi1 = y1 - 1;
    int zi = zp0 - 1, zj = zp1 - 1;
    float ax0 = ((unsigned)xi0 < (unsigned)W) ? dx       : 0.f;
    float ax1 = ((unsigned)xi1 < (unsigned)W) ? 1.f - dx : 0.f;
    float ay0 = ((unsigned)yi0 < (unsigned)H) ? dy       : 0.f;
    float ay1 = ((unsigned)yi1 < (unsigned)H) ? 1.f - dy : 0.f;
    float az0 = ((unsigned)zi  < (unsigned)D) ? dz       : 0.f;
    float az1 = ((unsigned)zj  < (unsigned)D) ? 1.f - dz : 0.f;
    int xc0 = min(max(xi0, 0), W - 1), xc1 = min(max(xi1, 0), W - 1);
    int yc0 = min(max(yi0, 0), H - 1), yc1 = min(max(yi1, 0), H - 1);
    int zc0 = min(max(zi, 0), D - 1),  zc1 = min(max(zj, 0), D - 1);
    const float* r00 = I + (yc0 * W + xc0) * D;
    const float* r01 = I + (yc0 * W + xc1) * D;
    const float* r10 = I + (yc1 * W + xc0) * D;
    const float* r11 = I + (yc1 * W + xc1) * D;
    float s00 = az0 * r00[zc0] + az1 * r00[zc1];
    float s01 = az0 * r01[zc0] + az1 * r01[zc1];
    float s10 = az0 * r10[zc0] + az1 * r10[zc1];
    float s11 = az0 * r11[zc0] + az1 * r11[zc1];
    return ay0 * (ax0 * s00 + ax1 * s01) + ay1 * (ax0 * s10 + ax1 * s11);
}

__global__ __launch_bounds__(512) void st_tile(
    const float* __restrict__ I,
    const float* __restrict__ dxt,
    const float* __restrict__ dyt,
    const float* __restrict__ dzt,
    float* __restrict__ out)
{
    __shared__ float tile[TILE_N];   // 54 KB -> 2 wg/CU, 16 waves/CU

    const int tid = threadIdx.x;
    const int bx = blockIdx.x, by = blockIdx.y, bz = blockIdx.z;
    const int w0 = bx * BW, h0 = by * BH, z0 = bz * BZ;
    const int xg0 = w0 - 4, yg0 = h0 - 4, zg0 = z0 - 4;

    // ---- staging: global_load_lds, per-lane CLAMPED source, linear LDS dest ----
    // chunk c (16B) holds tile dwords [4c,4c+3] = row c/6, z-segment (c%6)*4.
    // z-chunks are 4-aligned => every chunk is fully-valid or fully-dead (zero-weight).
    {
        const unsigned wv = tid >> 6, lane = tid & 63;
        for (unsigned i = wv; i < (unsigned)NINSTR; i += 8) {
            unsigned c = i * 64u + lane;
            unsigned row = c / 6u;           // compiler magic-mul
            unsigned s = c - row * 6u;
            unsigned ry = row / 24u;
            unsigned rx = row - ry * 24u;
            int gy = min(max(yg0 + (int)ry, 0), H - 1);
            int gx = min(max(xg0 + (int)rx, 0), W - 1);
            int zs = min(max(zg0 + (int)(s * 4u), 0), D - 4);
            const float* src = I + ((gy * W + gx) * D + zs);
            __builtin_amdgcn_global_load_lds(
                (const __attribute__((address_space(1))) void*)src,
                (__attribute__((address_space(3))) void*)(tile + i * 256u),
                16, 0, 0);
        }
    }

    // displacement loads (independent of staging; in flight across it)
    const int zq = tid & 3, wloc = (tid >> 2) & 15, hl0 = tid >> 6;
    const int wg = w0 + wloc;
    float4 vx[2], vy[2], vz[2];
    #pragma unroll
    for (int k = 0; k < 2; ++k) {
        int hg = h0 + hl0 + 8 * k;
        int t4 = (hg * W + wg) * (D / 4) + (z0 >> 2) + zq;
        vx[k] = reinterpret_cast<const float4*>(dxt)[t4];
        vy[k] = reinterpret_cast<const float4*>(dyt)[t4];
        vz[k] = reinterpret_cast<const float4*>(dzt)[t4];
    }

    asm volatile("s_waitcnt vmcnt(0)" ::: "memory");
    __syncthreads();

    // ---- unified compute: full reference clamp semantics (R3/R4-verified) ----
    float ro[2][4];
    #pragma unroll
    for (int k = 0; k < 2; ++k) {
        const int hg = h0 + hl0 + 8 * k;
        float rxj[4] = {vx[k].x, vx[k].y, vx[k].z, vx[k].w};
        float ryj[4] = {vy[k].x, vy[k].y, vy[k].z, vy[k].w};
        float rzj[4] = {vz[k].x, vz[k].y, vz[k].z, vz[k].w};

        #pragma unroll
        for (int j = 0; j < 4; ++j) {
            const int zv = z0 + zq * 4 + j;
            float x  = rxj[j] + (float)(wg + 1);
            float y  = ryj[j] + (float)(hg + 1);
            float zf = rzj[j] + (float)(zv + 1);

            int fx = (int)floorf(x), fy = (int)floorf(y), fz = (int)floorf(zf);
            int x0 = min(max(fx, 0), W + 1), x1 = min(max(fx + 1, 0), W + 1);
            int y0 = min(max(fy, 0), H + 1), y1 = min(max(fy + 1, 0), H + 1);
            int zp0 = min(max(fz, 0), D + 1), zp1 = min(max(fz + 1, 0), D + 1);

            float dx = (float)x1 - x, dy = (float)y1 - y, dz = (float)zp1 - zf;

            int xi0 = x0 - 1, xi1 = x1 - 1, yi0 = y0 - 1, yi1 = y1 - 1;
            int zi = zp0 - 1, zj2 = zp1 - 1;

            float ax0 = ((unsigned)xi0 < (unsigned)W) ? dx       : 0.f;
            float ax1 = ((unsigned)xi1 < (unsigned)W) ? 1.f - dx : 0.f;
            float ay0 = ((unsigned)yi0 < (unsigned)H) ? dy       : 0.f;
            float ay1 = ((unsigned)yi1 < (unsigned)H) ? 1.f - dy : 0.f;
            float az0 = ((unsigned)zi  < (unsigned)D) ? dz       : 0.f;
            float az1 = ((unsigned)zj2 < (unsigned)D) ? 1.f - dz : 0.f;

            int xc0 = min(max(xi0, 0), W - 1), xc1 = min(max(xi1, 0), W - 1);
            int yc0 = min(max(yi0, 0), H - 1), yc1 = min(max(yi1, 0), H - 1);
            int zc  = min(max(zi, 0), D - 2);

            bool zlo = (zi <= D - 2);
            bool zhi = (zi >= 0);

            int lx0 = xc0 - xg0, lx1 = xc1 - xg0;
            int ly0 = yc0 - yg0, ly1 = yc1 - yg0;
            int lz  = zc - zg0;

            bool ok = ((unsigned)lx0 <= (unsigned)(TX - 1))
                    & ((unsigned)lx1 <= (unsigned)(TX - 1))
                    & ((unsigned)ly0 <= (unsigned)(TY - 1))
                    & ((unsigned)ly1 <= (unsigned)(TY - 1))
                    & ((unsigned)lz  <= (unsigned)(TZ - 2));

            // clamp bases so LDS loads are always legal; bad lanes overwritten below
            int b00 = min(max((ly0 * TX + lx0) * TZ + lz, 0), TILE_N - 2);
            int b01 = min(max((ly0 * TX + lx1) * TZ + lz, 0), TILE_N - 2);
            int b10 = min(max((ly1 * TX + lx0) * TZ + lz, 0), TILE_N - 2);
            int b11 = min(max((ly1 * TX + lx1) * TZ + lz, 0), TILE_N - 2);

            float a0 = tile[b00], a1 = tile[b00 + 1];
            float b0 = tile[b01], b1 = tile[b01 + 1];
            float c0 = tile[b10], c1 = tile[b10 + 1];
            float d0 = tile[b11], d1 = tile[b11 + 1];

            float v000 = zlo ? a0 : a1, v001 = zhi ? a1 : a0;
            float v010 = zlo ? b0 : b1, v011 = zhi ? b1 : b0;
            float v100 = zlo ? c0 : c1, v101 = zhi ? c1 : c0;
            float v110 = zlo ? d0 : d1, v111 = zhi ? d1 : d0;
            float s00 = az0 * v000 + az1 * v001;
            float s01 = az0 * v010 + az1 * v011;
            float s10 = az0 * v100 + az1 * v101;
            float s11 = az0 * v110 + az1 * v111;
            float r = ay0 * (ax0 * s00 + ax1 * s01)
                    + ay1 * (ax0 * s10 + ax1 * s11);

            ro[k][j] = __builtin_expect(ok, 1) ? r : ref_voxel(I, x, y, zf);
        }
    }

    // ---- stores: lane-consecutive over (wloc,zq) -> 64B segments ----
    #pragma unroll
    for (int k = 0; k < 2; ++k) {
        int hg = h0 + hl0 + 8 * k;
        int t4 = (hg * W + wg) * (D / 4) + (z0 >> 2) + zq;
        reinterpret_cast<float4*>(out)[t4] =
            make_float4(ro[k][0], ro[k][1], ro[k][2], ro[k][3]);
    }
}

extern "C" void kernel_launch(void* const* d_in, const int* in_sizes, int n_in,
                              void* d_out, int out_size, void* d_ws, size_t ws_size,
                              hipStream_t stream) {
    const float* I   = (const float*)d_in[0];
    const float* dxt = (const float*)d_in[1];
    const float* dyt = (const float*)d_in[2];
    const float* dzt = (const float*)d_in[3];
    float* out = (float*)d_out;

    dim3 grid(W / BW, H / BH, D / BZ);   // 12 x 12 x 12
    hipLaunchKernelGGL(st_tile, grid, dim3(512), 0, stream,
                       I, dxt, dyt, dzt, out);
}